// Round 1
// baseline (522.921 us; speedup 1.0000x reference)
//
#include <hip/hip_runtime.h>
#include <stdint.h>

// Problem: h1[b,o] = sum_{i,j,k} t_i a_j v_k W1[o, i*97*97 + j*97 + k],
//          t/a/v = [1, modality_x[b,:]],  then 2-layer MLP.
// W1 flat index = (o*97 + i)*9409 + j*97 + k  ->  block blk = o*97+i owns a
// CONTIGUOUS 9409-float span. Inner k-contraction (k=1..96) is a K=96 bf16
// MFMA GEMM vs video; k=0/j=0/i=0 are bias terms (the prepended ones).

#define HID   96
#define NP1   97
#define ROWLEN 9409      // 97*97, floats per (o,i) tile
#define NBLK  9312       // 96*97 blocks
#define BATCH 64

typedef short bf16x8 __attribute__((ext_vector_type(8)));
typedef float f32x4  __attribute__((ext_vector_type(4)));

__device__ __forceinline__ short f2bf(float x) {
    union { float f; uint32_t u; } c; c.f = x;
    uint32_t r = (c.u + 0x7FFFu + ((c.u >> 16) & 1u)) >> 16;   // RNE
    return (short)(uint16_t)r;
}

__global__ __launch_bounds__(256)
void fusion_gemm(const float* __restrict__ W1,
                 const float* __restrict__ text_x,
                 const float* __restrict__ audio_x,
                 const float* __restrict__ video_x,
                 float* __restrict__ h1pre)   // [96][64] accumulator (pre-zeroed)
{
    __shared__ __align__(16) float Ws[9416];
    const int tid = threadIdx.x;
    const int blk = blockIdx.x;          // = o*97 + i
    const int o = blk / 97;
    const int i = blk - o * 97;

    // ---- stage contiguous W tile [blk*9409, +9409) via aligned float4 ----
    const long tile_start = (long)blk * ROWLEN;
    const int  shift = (int)(tile_start & 3);        // 0..3 float misalignment
    const float4* Wg4 = reinterpret_cast<const float4*>(W1 + (tile_start - shift));
    // (shift + 9409 + 3) >> 2 == 2353 for all shift in 0..3
#pragma unroll
    for (int it = 0; it < 9; ++it) {                 // 9*256 = 2304 unconditional
        int idx = it * 256 + tid;
        *reinterpret_cast<float4*>(&Ws[idx << 2]) = Wg4[idx];
    }
    {
        int idx = 2304 + tid;
        if (idx < 2353) *reinterpret_cast<float4*>(&Ws[idx << 2]) = Wg4[idx];
    }

    const int lane = tid & 63;
    const int wave = tid >> 6;
    const int quad = lane >> 4;
    const int col  = lane & 15;
    const int b    = wave * 16 + col;    // this wave's batch tile: b in [wave*16, +16)

    // ---- B fragments: video[b][k], K=96 = 3 k-steps of 32 (fp32->bf16) ----
    // B-frag layout: lane holds B[k = quad*8+e][n = lane&15], e = 0..7
    bf16x8 bfrag[3];
#pragma unroll
    for (int ks = 0; ks < 3; ++ks) {
        const float* vp = video_x + b * HID + ks * 32 + quad * 8;
        float4 v0 = *reinterpret_cast<const float4*>(vp);
        float4 v1 = *reinterpret_cast<const float4*>(vp + 4);
        bf16x8 f;
        f[0]=f2bf(v0.x); f[1]=f2bf(v0.y); f[2]=f2bf(v0.z); f[3]=f2bf(v0.w);
        f[4]=f2bf(v1.x); f[5]=f2bf(v1.y); f[6]=f2bf(v1.z); f[7]=f2bf(v1.w);
        bfrag[ks] = f;
    }

    __syncthreads();

    // ---- MFMA: U[j, b] = sum_{k=0..95} W[j, 1+k] * video[b, k] ----
    // 97 j-rows -> 7 m-tiles of 16 (tile 6: only j=96 valid, clamped reads,
    // garbage rows are zero-weighted in the epilogue).
    f32x4 acc[7];
#pragma unroll
    for (int mt = 0; mt < 7; ++mt) acc[mt] = (f32x4){0.f, 0.f, 0.f, 0.f};

#pragma unroll
    for (int ks = 0; ks < 3; ++ks) {
#pragma unroll
        for (int mt = 0; mt < 7; ++mt) {
            int j  = mt * 16 + col;                 // A-frag row: m = lane&15
            int je = j > 96 ? 96 : j;
            const float* ap = &Ws[shift + je * NP1 + 1 + ks * 32 + quad * 8];
            bf16x8 af;
#pragma unroll
            for (int e = 0; e < 8; ++e) af[e] = f2bf(ap[e]);
            acc[mt] = __builtin_amdgcn_mfma_f32_16x16x32_bf16(af, bfrag[ks], acc[mt], 0, 0, 0);
        }
    }

    // ---- epilogue: S[b] = sum_j a[b,j] * (U[j,b] + W[j,0]) ----
    // D layout (verified m89/m91): col = lane&15 -> b,  row = quad*4 + reg -> j
    float s = 0.f;
#pragma unroll
    for (int mt = 0; mt < 7; ++mt) {
#pragma unroll
        for (int r = 0; r < 4; ++r) {
            int j = mt * 16 + quad * 4 + r;
            if (j < 97) {
                float u  = acc[mt][r] + Ws[shift + j * NP1];          // + k=0 bias
                float aw = (j == 0) ? 1.f : audio_x[b * HID + (j - 1)];
                s += u * aw;
            }
        }
    }
    s += __shfl_xor(s, 16);
    s += __shfl_xor(s, 32);   // all quads now hold full sum over j

    if (quad == 0) {
        float tw = (i == 0) ? 1.f : text_x[b * HID + (i - 1)];
        atomicAdd(&h1pre[o * BATCH + b], s * tw);
    }
}

__global__ __launch_bounds__(64)
void mlp_tail(const float* __restrict__ h1pre, const float* __restrict__ b1,
              const float* __restrict__ W2, const float* __restrict__ b2,
              const float* __restrict__ W3, const float* __restrict__ b3,
              float* __restrict__ out)
{
    __shared__ float h1s[96];
    __shared__ float h2s[48];
    const int b = blockIdx.x;
    const int t = threadIdx.x;
    for (int o = t; o < 96; o += 64) {
        float v = h1pre[o * BATCH + b] + b1[o];
        h1s[o] = v > 0.f ? v : 0.f;
    }
    __syncthreads();
    if (t < 48) {
        float acc = b2[t];
#pragma unroll 8
        for (int o = 0; o < 96; ++o) acc += W2[t * 96 + o] * h1s[o];
        h2s[t] = acc > 0.f ? acc : 0.f;
    }
    __syncthreads();
    if (t < 3) {
        float acc = b3[t];
#pragma unroll
        for (int c = 0; c < 48; ++c) acc += W3[t * 48 + c] * h2s[c];
        out[b * 3 + t] = acc;
    }
}

extern "C" void kernel_launch(void* const* d_in, const int* in_sizes, int n_in,
                              void* d_out, int out_size, void* d_ws, size_t ws_size,
                              hipStream_t stream)
{
    const float* text  = (const float*)d_in[0];
    const float* audio = (const float*)d_in[1];
    const float* video = (const float*)d_in[2];
    const float* W1    = (const float*)d_in[3];
    const float* b1    = (const float*)d_in[4];
    const float* W2    = (const float*)d_in[5];
    const float* b2    = (const float*)d_in[6];
    const float* W3    = (const float*)d_in[7];
    const float* b3    = (const float*)d_in[8];
    float* h1pre = (float*)d_ws;                       // 96*64 fp32 = 24.6 KB

    hipMemsetAsync(h1pre, 0, HID * BATCH * sizeof(float), stream);
    fusion_gemm<<<NBLK, 256, 0, stream>>>(W1, text, audio, video, h1pre);
    mlp_tail<<<BATCH, 64, 0, stream>>>(h1pre, b1, W2, b2, W3, b3, (float*)d_out);
}